// Round 2
// baseline (169.989 us; speedup 1.0000x reference)
//
#include <hip/hip_runtime.h>

// VectorQuantizer forward: out = codebook[argmin_k ||x - e_k||^2]
// R8: R7 (resident-B K-split GEMM) with the spill catastrophe fixed.
//     R7's __launch_bounds__(256,2) capped VGPRs at 128 while the design
//     needs ~235 (BH/BL resident = 128 VGPRs) -> ~90 spilled regs ->
//     +41 MB scratch writes / +120 MB scratch reads per dispatch (rocprof:
//     WRITE 73.7 MB vs 32.8 MB output). Now __launch_bounds__(256,1):
//     ~235 VGPR, 2 waves/SIMD, 2 blocks/CU (grid 512 = exactly resident).
//     Steady-state loop has zero per-iteration global loads, so 8 waves/CU
//     suffices. Same 3-term bf16 split (lo*lo dropped, err ~2e-5 in c-space)
//     + exact fp32 fallback for rows with best1/best2 c-gap <= TAU/2 =>
//     committed argmins identical to fp32 path.

#define KC 512
#define DD 64
#define TAU 5e-4f
#define HTAU (0.5f * TAU)    // threshold in c-space (s = -2c)

typedef __attribute__((ext_vector_type(8))) short short8;
typedef __attribute__((ext_vector_type(4))) float float4v;

__device__ inline unsigned short f2bf(float f) {   // RNE bf16
    unsigned u = __float_as_uint(f);
    return (unsigned short)((u + 0x7FFF + ((u >> 16) & 1)) >> 16);
}
__device__ inline float bf2f(unsigned short b) {
    return __uint_as_float((unsigned)b << 16);
}

// Per code-tile ct (16 codes): bias (exact fp32, sequential d), et (fp32
// transposed codebook for gather/fallback), and Bh/Bl bf16 packs laid out in
// the exact 16x16x32 B-fragment order: element (lane l, j) = E[kc*32 +
// (l>>4)*8 + j][ct*16 + (l&15)].
__global__ __launch_bounds__(256) void vq_prep(const float* __restrict__ emb,
                                               float* __restrict__ et,
                                               float* __restrict__ bias,
                                               short* __restrict__ Bh,
                                               short* __restrict__ Bl) {
    __shared__ float tile[DD][17];
    const int ct = blockIdx.x;            // 0..31
    const int t  = threadIdx.x;

    {   // stage emb[d][ct*16..+16] -> tile[d][c]
        const int d = t >> 2, c0 = (t & 3) * 4;
        float4 v = *(const float4*)(emb + (size_t)d * KC + ct * 16 + c0);
        tile[d][c0 + 0] = v.x; tile[d][c0 + 1] = v.y;
        tile[d][c0 + 2] = v.z; tile[d][c0 + 3] = v.w;
    }
    __syncthreads();

    if (t < 16) {   // bias, exact sequential d-order
        float s = 0.f;
        #pragma unroll
        for (int d = 0; d < DD; ++d) { float v = tile[d][t]; s += v * v; }
        bias[ct * 16 + t] = s;
    }

    {   // et[(ct*16+c)][d0..d0+3]
        const int c = t >> 4, d0 = (t & 15) * 4;
        float4 v;
        v.x = tile[d0 + 0][c]; v.y = tile[d0 + 1][c];
        v.z = tile[d0 + 2][c]; v.w = tile[d0 + 3][c];
        *(float4*)(et + (size_t)(ct * 16 + c) * DD + d0) = v;
    }

    {   // B-fragment packs
        const int term = t >> 7;          // 0 = hi, 1 = lo
        const int kc   = (t >> 6) & 1;
        const int l    = t & 63;
        const int c    = l & 15, dq = l >> 4;
        short v8[8];
        #pragma unroll
        for (int j = 0; j < 8; ++j) {
            float f = tile[kc * 32 + dq * 8 + j][c];
            unsigned short h = f2bf(f);
            v8[j] = (short)(term == 0 ? h : f2bf(f - bf2f(h)));
        }
        short* dst = (term == 0 ? Bh : Bl) + ((size_t)(ct * 2 + kc) * 64 + l) * 8;
        *(short8*)dst = *(short8*)v8;
    }
}

// Block = 256 threads / 4 waves, covers 256 rows as 8 x 32-row tiles.
// Wave w owns codes [w*128, w*128+128) (ct = w*8 .. w*8+8), resident in VGPR.
__global__ __launch_bounds__(256, 1) void vq_main(const float* __restrict__ x_in,
                                                  const short* __restrict__ Bh,
                                                  const short* __restrict__ Bl,
                                                  const float* __restrict__ bias,
                                                  const float* __restrict__ et,
                                                  float* __restrict__ out) {
    // A tile double buffer, fragment order: frag f=(rt*2+kc)*2+term, lane l,
    // 8 bf16 each -> contiguous per-wave ds_read_b128 / ds_write_b128.
    __shared__ __align__(16) short A_lds[2][8][512];
    __shared__ float pv1[4][256];
    __shared__ float pv2[4][256];
    __shared__ int   pkk[4][256];
    __shared__ int   k1s[256];
    __shared__ float gaps[256];

    const int t = threadIdx.x, w = t >> 6, l = t & 63;
    const int col = l & 15, quad = l >> 4;
    const int R0 = blockIdx.x * 256;

    // ---- resident B fragments: this wave's 128 codes (32 short8 = 128 VGPR)
    short8 BH[8][2], BL[8][2];
    #pragma unroll
    for (int cl = 0; cl < 8; ++cl)
        #pragma unroll
        for (int kc = 0; kc < 2; ++kc) {
            BH[cl][kc] = *(const short8*)(Bh + ((size_t)((w * 8 + cl) * 2 + kc) * 64 + l) * 8);
            BL[cl][kc] = *(const short8*)(Bl + ((size_t)((w * 8 + cl) * 2 + kc) * 64 + l) * 8);
        }
    float bhalf[8];   // -0.5 * ||e||^2 for this lane's code in each ct
    #pragma unroll
    for (int cl = 0; cl < 8; ++cl)
        bhalf[cl] = -0.5f * bias[(w * 8 + cl) * 16 + col];

    // staging role: wave w produces fragment pair (rt = w>>1, kc = w&1)
    const int s_row = (w >> 1) * 16 + col;          // row within 32-row tile
    const int s_d   = (w & 1) * 32 + quad * 8;      // d offset
    const int fh = w * 2, flo = w * 2 + 1;          // frag indices (hi, lo)

    {   // stage tile 0
        const float* p = x_in + (size_t)(R0 + s_row) * DD + s_d;
        float4 xa = *(const float4*)p;
        float4 xb = *(const float4*)(p + 4);
        float f[8] = {xa.x, xa.y, xa.z, xa.w, xb.x, xb.y, xb.z, xb.w};
        short8 hi8, lo8;
        #pragma unroll
        for (int j = 0; j < 8; ++j) {
            unsigned short h = f2bf(f[j]);
            hi8[j] = (short)h;
            lo8[j] = (short)f2bf(f[j] - bf2f(h));
        }
        *(short8*)&A_lds[0][fh][l * 8]  = hi8;
        *(short8*)&A_lds[0][flo][l * 8] = lo8;
    }
    __syncthreads();

    #pragma unroll 1
    for (int tt = 0; tt < 8; ++tt) {
        const int cur = tt & 1;

        // T14 issue-early: next tile's global loads, consumed after compute
        float4 nxa, nxb;
        if (tt < 7) {
            const float* p = x_in + (size_t)(R0 + (tt + 1) * 32 + s_row) * DD + s_d;
            nxa = *(const float4*)p;
            nxb = *(const float4*)(p + 4);
        }

        // A fragments for this tile (8 x ds_read_b128, contiguous)
        short8 ah[2][2], al[2][2];
        #pragma unroll
        for (int rt = 0; rt < 2; ++rt)
            #pragma unroll
            for (int kc = 0; kc < 2; ++kc) {
                ah[rt][kc] = *(const short8*)&A_lds[cur][(rt * 2 + kc) * 2 + 0][l * 8];
                al[rt][kc] = *(const short8*)&A_lds[cur][(rt * 2 + kc) * 2 + 1][l * 8];
            }

        // per-(row,code-lane) running max1/max2/k in c-space (c = x.e - b/2)
        float m1[2][4], m2[2][4];
        int   kb[2][4];
        #pragma unroll
        for (int rt = 0; rt < 2; ++rt)
            #pragma unroll
            for (int r = 0; r < 4; ++r) {
                m1[rt][r] = -3.4e38f; m2[rt][r] = -3.4e38f; kb[rt][r] = 0;
            }

        #pragma unroll
        for (int cl = 0; cl < 8; ++cl) {
            const int kk = (w * 8 + cl) * 16 + col;
            #pragma unroll
            for (int rt = 0; rt < 2; ++rt) {
                float4v c = {bhalf[cl], bhalf[cl], bhalf[cl], bhalf[cl]};
                c = __builtin_amdgcn_mfma_f32_16x16x32_bf16(ah[rt][0], BH[cl][0], c, 0, 0, 0);
                c = __builtin_amdgcn_mfma_f32_16x16x32_bf16(ah[rt][1], BH[cl][1], c, 0, 0, 0);
                c = __builtin_amdgcn_mfma_f32_16x16x32_bf16(al[rt][0], BH[cl][0], c, 0, 0, 0);
                c = __builtin_amdgcn_mfma_f32_16x16x32_bf16(al[rt][1], BH[cl][1], c, 0, 0, 0);
                c = __builtin_amdgcn_mfma_f32_16x16x32_bf16(ah[rt][0], BL[cl][0], c, 0, 0, 0);
                c = __builtin_amdgcn_mfma_f32_16x16x32_bf16(ah[rt][1], BL[cl][1], c, 0, 0, 0);
                #pragma unroll
                for (int r = 0; r < 4; ++r) {
                    float cr = c[r];
                    bool gt = cr > m1[rt][r];                    // strict: first-min k
                    m2[rt][r] = fmaxf(fminf(cr, m1[rt][r]), m2[rt][r]);
                    kb[rt][r] = gt ? kk : kb[rt][r];
                    m1[rt][r] = fmaxf(m1[rt][r], cr);
                }
            }
        }

        // reduce over the 16 code-lanes; write per-(row,wave) partials
        #pragma unroll
        for (int rt = 0; rt < 2; ++rt)
            #pragma unroll
            for (int r = 0; r < 4; ++r) {
                float b1 = m1[rt][r], b2 = m2[rt][r];
                int   bk = kb[rt][r];
                #pragma unroll
                for (int m = 1; m <= 8; m <<= 1) {
                    float o1 = __shfl_xor(b1, m, 64);
                    float o2 = __shfl_xor(b2, m, 64);
                    int   ok = __shfl_xor(bk, m, 64);
                    float n2 = fmaxf(fmaxf(b2, o2), fminf(b1, o1));
                    bool take = (o1 > b1) || (o1 == b1 && ok < bk);
                    b1 = take ? o1 : b1;
                    bk = take ? ok : bk;
                    b2 = n2;
                }
                if (col == 0) {
                    const int rowg = tt * 32 + rt * 16 + quad * 4 + r;
                    pv1[w][rowg] = b1;
                    pv2[w][rowg] = b2;
                    pkk[w][rowg] = bk;
                }
            }

        if (tt < 7) {   // convert (waits vmcnt here) + write-late into next buf
            float f[8] = {nxa.x, nxa.y, nxa.z, nxa.w, nxb.x, nxb.y, nxb.z, nxb.w};
            short8 hi8, lo8;
            #pragma unroll
            for (int j = 0; j < 8; ++j) {
                unsigned short h = f2bf(f[j]);
                hi8[j] = (short)h;
                lo8[j] = (short)f2bf(f[j] - bf2f(h));
            }
            __syncthreads();   // everyone done reading buf cur^1 (prev tile)
            *(short8*)&A_lds[cur ^ 1][fh][l * 8]  = hi8;
            *(short8*)&A_lds[cur ^ 1][flo][l * 8] = lo8;
            __syncthreads();   // next tile's fragments ready
        }
    }
    __syncthreads();   // last tile's partials visible

    {   // cross-wave combine (thread t = block row), ascending-k wave order
        float b1 = pv1[0][t], b2 = pv2[0][t];
        int   bk = pkk[0][t];
        #pragma unroll
        for (int wv = 1; wv < 4; ++wv) {
            float v1 = pv1[wv][t], v2 = pv2[wv][t];
            int   vk = pkk[wv][t];
            bool gt = v1 > b1;                       // strict: lower wave keeps ties
            float nb2 = gt ? fmaxf(b1, v2) : fmaxf(b2, v1);
            bk = gt ? vk : bk;
            b1 = gt ? v1 : b1;
            b2 = nb2;
        }
        k1s[t]  = bk;
        gaps[t] = b1 - b2;                           // c-space gap = s-gap / 2
    }
    __syncthreads();

    {   // exact fp32 fallback for near-tie rows (ballot-driven, rare).
        // Lane l scans codes [8l,8l+8) ascending; cross-lane tie-break = lower
        // k => numpy first-min semantics, independent of the approx path.
        unsigned long long mask = __ballot(gaps[w * 64 + l] <= HTAU);
        while (mask) {
            const int rr = __builtin_ctzll(mask);
            mask &= mask - 1;
            const int row_l = w * 64 + rr;
            const size_t grow = (size_t)(R0 + row_l) * DD;
            const int kbase = l * 8;
            float acc[8];
            #pragma unroll
            for (int j = 0; j < 8; ++j) acc[j] = 0.f;
            for (int d0 = 0; d0 < DD; d0 += 4) {
                float4 xv = *(const float4*)(x_in + grow + d0);
                #pragma unroll
                for (int j = 0; j < 8; ++j) {
                    float4 ev = *(const float4*)(et + (size_t)(kbase + j) * DD + d0);
                    acc[j] += xv.x * ev.x;
                    acc[j] += xv.y * ev.y;
                    acc[j] += xv.z * ev.z;
                    acc[j] += xv.w * ev.w;
                }
            }
            float4 b0 = *(const float4*)(bias + kbase);
            float4 b1v = *(const float4*)(bias + kbase + 4);
            float bb[8] = {b0.x, b0.y, b0.z, b0.w, b1v.x, b1v.y, b1v.z, b1v.w};
            float bv = 3.4e38f; int bk = 0;
            #pragma unroll
            for (int j = 0; j < 8; ++j) {
                float s = bb[j] - 2.f * acc[j];
                if (s < bv) { bv = s; bk = kbase + j; }
            }
            #pragma unroll
            for (int m = 1; m <= 32; m <<= 1) {
                float ov = __shfl_xor(bv, m, 64);
                int   ok = __shfl_xor(bk, m, 64);
                if (ov < bv || (ov == bv && ok < bk)) { bv = ov; bk = ok; }
            }
            if (l == 0) k1s[row_l] = bk;
        }
    }
    __syncthreads();

    {   // gather epilogue: 16 lanes per row -> contiguous 256 B stores
        const int c4 = (t & 15) * 4;
        const int rg = t >> 4;
        #pragma unroll
        for (int i = 0; i < 16; ++i) {
            const int row = i * 16 + rg;
            const int bk = k1s[row];
            float4 v = *(const float4*)(et + (size_t)bk * DD + c4);
            *(float4*)(out + (size_t)(R0 + row) * DD + c4) = v;
        }
    }
}

extern "C" void kernel_launch(void* const* d_in, const int* in_sizes, int n_in,
                              void* d_out, int out_size, void* d_ws, size_t ws_size,
                              hipStream_t stream) {
    const float* x_in = (const float*)d_in[0];   // [131072, 64]
    const float* emb  = (const float*)d_in[1];   // [64, 512]
    float* out = (float*)d_out;

    float* et   = (float*)d_ws;                       // 512*64 f32 = 131072 B
    float* bias = et + KC * DD;                       // 2048 B
    short* Bh   = (short*)(bias + KC);                // 32*2*64*8 shorts = 64 KB
    short* Bl   = Bh + 32 * 2 * 64 * 8;               // 64 KB

    const int N = out_size / DD;                      // 131072 rows

    vq_prep<<<32, 256, 0, stream>>>(emb, et, bias, Bh, Bl);
    vq_main<<<N / 256, 256, 0, stream>>>(x_in, Bh, Bl, bias, et, out);
}

// Round 3
// 126.729 us; speedup vs baseline: 1.3414x; 1.3414x over previous
//
#include <hip/hip_runtime.h>

// VectorQuantizer forward: out = codebook[argmin_k ||x - e_k||^2]
// R9: barrier-free sweep. R8 was latency-bound (all pipes <25%, occupancy
//     9%): resident-B-in-VGPR forced 2 waves/SIMD and the tile loop paid
//     2 barriers + a 96-shuffle reduce + LDS partial round-trip per 32 rows.
//     Now B (Bh+Bl+bias, 130 KB) is staged ONCE into LDS per block; each of
//     8 waves holds 64 rows in registers (16 short8 after one-time bf16
//     split) and sweeps all 512 codes with {4 ds_read_b128 + 24 MFMA +
//     argmin} per 16-code tile -- zero barriers in the hot loop, one
//     shuffle-reduce per wave at the end, no cross-wave combine. Same
//     3-term bf16 split (lo*lo dropped, err ~2e-5 in c-space) + exact fp32
//     fallback for rows with best1/best2 c-gap <= TAU/2 => committed argmins
//     identical to fp32 path.

#define KC 512
#define DD 64
#define TAU 5e-4f
#define HTAU (0.5f * TAU)    // threshold in c-space (s = -2c)

typedef __attribute__((ext_vector_type(8))) short short8;
typedef __attribute__((ext_vector_type(4))) float float4v;

__device__ inline unsigned short f2bf(float f) {   // RNE bf16
    unsigned u = __float_as_uint(f);
    return (unsigned short)((u + 0x7FFF + ((u >> 16) & 1)) >> 16);
}
__device__ inline float bf2f(unsigned short b) {
    return __uint_as_float((unsigned)b << 16);
}

// Per code-tile ct (16 codes): bias (exact fp32, sequential d), et (fp32
// transposed codebook for gather/fallback), and Bh/Bl bf16 packs laid out in
// the exact 16x16x32 B-fragment order: element (lane l, j) = E[kc*32 +
// (l>>4)*8 + j][ct*16 + (l&15)].
__global__ __launch_bounds__(256) void vq_prep(const float* __restrict__ emb,
                                               float* __restrict__ et,
                                               float* __restrict__ bias,
                                               short* __restrict__ Bh,
                                               short* __restrict__ Bl) {
    __shared__ float tile[DD][17];
    const int ct = blockIdx.x;            // 0..31
    const int t  = threadIdx.x;

    {   // stage emb[d][ct*16..+16] -> tile[d][c]
        const int d = t >> 2, c0 = (t & 3) * 4;
        float4 v = *(const float4*)(emb + (size_t)d * KC + ct * 16 + c0);
        tile[d][c0 + 0] = v.x; tile[d][c0 + 1] = v.y;
        tile[d][c0 + 2] = v.z; tile[d][c0 + 3] = v.w;
    }
    __syncthreads();

    if (t < 16) {   // bias, exact sequential d-order
        float s = 0.f;
        #pragma unroll
        for (int d = 0; d < DD; ++d) { float v = tile[d][t]; s += v * v; }
        bias[ct * 16 + t] = s;
    }

    {   // et[(ct*16+c)][d0..d0+3]
        const int c = t >> 4, d0 = (t & 15) * 4;
        float4 v;
        v.x = tile[d0 + 0][c]; v.y = tile[d0 + 1][c];
        v.z = tile[d0 + 2][c]; v.w = tile[d0 + 3][c];
        *(float4*)(et + (size_t)(ct * 16 + c) * DD + d0) = v;
    }

    {   // B-fragment packs
        const int term = t >> 7;          // 0 = hi, 1 = lo
        const int kc   = (t >> 6) & 1;
        const int l    = t & 63;
        const int c    = l & 15, dq = l >> 4;
        short v8[8];
        #pragma unroll
        for (int j = 0; j < 8; ++j) {
            float f = tile[kc * 32 + dq * 8 + j][c];
            unsigned short h = f2bf(f);
            v8[j] = (short)(term == 0 ? h : f2bf(f - bf2f(h)));
        }
        short* dst = (term == 0 ? Bh : Bl) + ((size_t)(ct * 2 + kc) * 64 + l) * 8;
        *(short8*)dst = *(short8*)v8;
    }
}

// Block = 512 threads / 8 waves, covers 512 rows; wave w owns rows
// [w*64, w*64+64) in registers and sweeps all 512 codes from LDS.
__global__ __launch_bounds__(512, 2) void vq_main(const float* __restrict__ x_in,
                                                  const short* __restrict__ Bh,
                                                  const short* __restrict__ Bl,
                                                  const float* __restrict__ bias,
                                                  const float* __restrict__ et,
                                                  float* __restrict__ out) {
    __shared__ __align__(16) short Bh_lds[32 * 2 * 64 * 8];   // 64 KB
    __shared__ __align__(16) short Bl_lds[32 * 2 * 64 * 8];   // 64 KB
    __shared__ float bias_s[KC];                               // 2 KB
    __shared__ int   k1s[8][64];
    __shared__ float gaps[8][64];

    const int t = threadIdx.x, w = t >> 6, l = t & 63;
    const int col = l & 15, quad = l >> 4;
    const int R0 = blockIdx.x * 512;
    const int wrow0 = w * 64;

    {   // stage Bh/Bl/bias -> LDS (coalesced float4 copies)
        const float4* srcH = (const float4*)Bh;
        const float4* srcL = (const float4*)Bl;
        float4* dstH = (float4*)Bh_lds;
        float4* dstL = (float4*)Bl_lds;
        #pragma unroll
        for (int j = 0; j < 8; ++j) {
            const int idx = t + j * 512;              // 4096 float4 per array
            dstH[idx] = srcH[idx];
            dstL[idx] = srcL[idx];
        }
        bias_s[t] = bias[t];
    }

    // ---- A: this wave's 64 rows -> registers, bf16 hi/lo split (done once).
    // 16x16x32 A-layout: m = lane&15, k = quad*8 + j; rt = 16-row tile 0..3.
    short8 AH[4][2], AL[4][2];
    #pragma unroll
    for (int rt = 0; rt < 4; ++rt)
        #pragma unroll
        for (int kc = 0; kc < 2; ++kc) {
            const float* p = x_in + (size_t)(R0 + wrow0 + rt * 16 + col) * DD
                           + kc * 32 + quad * 8;
            float4 xa = *(const float4*)p;
            float4 xb = *(const float4*)(p + 4);
            float f[8] = {xa.x, xa.y, xa.z, xa.w, xb.x, xb.y, xb.z, xb.w};
            short8 hi8, lo8;
            #pragma unroll
            for (int j = 0; j < 8; ++j) {
                unsigned short h = f2bf(f[j]);
                hi8[j] = (short)h;
                lo8[j] = (short)f2bf(f[j] - bf2f(h));
            }
            AH[rt][kc] = hi8;
            AL[rt][kc] = lo8;
        }
    __syncthreads();   // B staged (the only block-wide barrier before reduce)

    // per-(row,code-lane) running max1/max2/k in c-space (c = x.e - b/2)
    float m1[4][4], m2[4][4];
    int   kb[4][4];
    #pragma unroll
    for (int rt = 0; rt < 4; ++rt)
        #pragma unroll
        for (int r = 0; r < 4; ++r) {
            m1[rt][r] = -3.4e38f; m2[rt][r] = -3.4e38f; kb[rt][r] = 0;
        }

    #pragma unroll 2
    for (int ct = 0; ct < 32; ++ct) {
        short8 bh0 = *(const short8*)&Bh_lds[((ct * 2 + 0) * 64 + l) * 8];
        short8 bh1 = *(const short8*)&Bh_lds[((ct * 2 + 1) * 64 + l) * 8];
        short8 bl0 = *(const short8*)&Bl_lds[((ct * 2 + 0) * 64 + l) * 8];
        short8 bl1 = *(const short8*)&Bl_lds[((ct * 2 + 1) * 64 + l) * 8];
        const float ci = -0.5f * bias_s[ct * 16 + col];
        const int kk = ct * 16 + col;
        #pragma unroll
        for (int rt = 0; rt < 4; ++rt) {
            float4v c = {ci, ci, ci, ci};
            c = __builtin_amdgcn_mfma_f32_16x16x32_bf16(AH[rt][0], bh0, c, 0, 0, 0);
            c = __builtin_amdgcn_mfma_f32_16x16x32_bf16(AH[rt][1], bh1, c, 0, 0, 0);
            c = __builtin_amdgcn_mfma_f32_16x16x32_bf16(AL[rt][0], bh0, c, 0, 0, 0);
            c = __builtin_amdgcn_mfma_f32_16x16x32_bf16(AL[rt][1], bh1, c, 0, 0, 0);
            c = __builtin_amdgcn_mfma_f32_16x16x32_bf16(AH[rt][0], bl0, c, 0, 0, 0);
            c = __builtin_amdgcn_mfma_f32_16x16x32_bf16(AH[rt][1], bl1, c, 0, 0, 0);
            #pragma unroll
            for (int r = 0; r < 4; ++r) {
                float cr = c[r];
                bool gt = cr > m1[rt][r];                    // strict: first-min k
                m2[rt][r] = fmaxf(fminf(cr, m1[rt][r]), m2[rt][r]);
                kb[rt][r] = gt ? kk : kb[rt][r];
                m1[rt][r] = fmaxf(m1[rt][r], cr);
            }
        }
    }

    // reduce over the 16 code-lanes (once per wave); C layout: row =
    // rt*16 + quad*4 + r, col = lane&15.
    #pragma unroll
    for (int rt = 0; rt < 4; ++rt)
        #pragma unroll
        for (int r = 0; r < 4; ++r) {
            float b1 = m1[rt][r], b2 = m2[rt][r];
            int   bk = kb[rt][r];
            #pragma unroll
            for (int m = 1; m <= 8; m <<= 1) {
                float o1 = __shfl_xor(b1, m, 64);
                float o2 = __shfl_xor(b2, m, 64);
                int   ok = __shfl_xor(bk, m, 64);
                float n2 = fmaxf(fmaxf(b2, o2), fminf(b1, o1));
                bool take = (o1 > b1) || (o1 == b1 && ok < bk);
                b1 = take ? o1 : b1;
                bk = take ? ok : bk;
                b2 = n2;
            }
            if (col == 0) {
                const int rowl = rt * 16 + quad * 4 + r;
                k1s[w][rowl]  = bk;
                gaps[w][rowl] = b1 - b2;     // c-space gap = s-gap / 2
            }
        }
    __syncthreads();   // make k1s/gaps visible (cheap, once)

    {   // exact fp32 fallback for near-tie rows (ballot-driven, rare).
        // Lane l scans codes [8l,8l+8) ascending; cross-lane tie-break =
        // lower k => numpy first-min semantics, independent of approx path.
        unsigned long long mask = __ballot(gaps[w][l] <= HTAU);
        while (mask) {
            const int rr = __builtin_ctzll(mask);
            mask &= mask - 1;
            const size_t grow = (size_t)(R0 + wrow0 + rr) * DD;
            const int kbase = l * 8;
            float acc[8];
            #pragma unroll
            for (int j = 0; j < 8; ++j) acc[j] = 0.f;
            for (int d0 = 0; d0 < DD; d0 += 4) {
                float4 xv = *(const float4*)(x_in + grow + d0);
                #pragma unroll
                for (int j = 0; j < 8; ++j) {
                    float4 ev = *(const float4*)(et + (size_t)(kbase + j) * DD + d0);
                    acc[j] += xv.x * ev.x;
                    acc[j] += xv.y * ev.y;
                    acc[j] += xv.z * ev.z;
                    acc[j] += xv.w * ev.w;
                }
            }
            float4 b0 = *(const float4*)(bias + kbase);
            float4 b1v = *(const float4*)(bias + kbase + 4);
            float bb[8] = {b0.x, b0.y, b0.z, b0.w, b1v.x, b1v.y, b1v.z, b1v.w};
            float bv = 3.4e38f; int bk = 0;
            #pragma unroll
            for (int j = 0; j < 8; ++j) {
                float s = bb[j] - 2.f * acc[j];
                if (s < bv) { bv = s; bk = kbase + j; }
            }
            #pragma unroll
            for (int m = 1; m <= 32; m <<= 1) {
                float ov = __shfl_xor(bv, m, 64);
                int   ok = __shfl_xor(bk, m, 64);
                if (ov < bv || (ov == bv && ok < bk)) { bv = ov; bk = ok; }
            }
            if (l == 0) k1s[w][rr] = bk;
        }
    }

    {   // gather epilogue (per wave, its own rows): 16 lanes per row
        const int c4 = col * 4;
        #pragma unroll
        for (int i = 0; i < 16; ++i) {
            const int rowl = i * 4 + quad;
            const int bk = k1s[w][rowl];
            float4 v = *(const float4*)(et + (size_t)bk * DD + c4);
            *(float4*)(out + (size_t)(R0 + wrow0 + rowl) * DD + c4) = v;
        }
    }
}

extern "C" void kernel_launch(void* const* d_in, const int* in_sizes, int n_in,
                              void* d_out, int out_size, void* d_ws, size_t ws_size,
                              hipStream_t stream) {
    const float* x_in = (const float*)d_in[0];   // [131072, 64]
    const float* emb  = (const float*)d_in[1];   // [64, 512]
    float* out = (float*)d_out;

    float* et   = (float*)d_ws;                       // 512*64 f32 = 131072 B
    float* bias = et + KC * DD;                       // 2048 B
    short* Bh   = (short*)(bias + KC);                // 32*2*64*8 shorts = 64 KB
    short* Bl   = Bh + 32 * 2 * 64 * 8;               // 64 KB

    const int N = out_size / DD;                      // 131072 rows

    vq_prep<<<32, 256, 0, stream>>>(emb, et, bias, Bh, Bl);
    vq_main<<<N / 512, 512, 0, stream>>>(x_in, Bh, Bl, bias, et, out);
}

// Round 4
// 126.368 us; speedup vs baseline: 1.3452x; 1.0029x over previous
//
#include <hip/hip_runtime.h>

// VectorQuantizer forward: out = codebook[argmin_k ||x - e_k||^2]
// R10: 16-wave blocks. R9 (8 waves/CU, 2/SIMD) was ~90% stalled: per-ct
//      dependent chain (ds_read ~120cy -> 6-deep MFMA chain -> argmin) with
//      only 2 waves/SIMD to hide it; all pipe-work sums to ~5 us vs 60 us
//      wall. LDS (137 KB) pins 1 block/CU, so waves come from block size:
//      1024 threads / 16 waves, 32 rows per wave (rt=2), 4 waves/SIMD.
//      Per-wave A-state halves (32 VGPR) -> fits the 128-VGPR cap a
//      1024-thread block requires. Hot loop / tie-break / TAU fallback
//      semantics unchanged from R9. Same 3-term bf16 split (lo*lo dropped,
//      err ~2e-5 in c-space) + exact fp32 fallback for rows with
//      best1/best2 c-gap <= TAU/2 => committed argmins identical to fp32.

#define KC 512
#define DD 64
#define TAU 5e-4f
#define HTAU (0.5f * TAU)    // threshold in c-space (s = -2c)

typedef __attribute__((ext_vector_type(8))) short short8;
typedef __attribute__((ext_vector_type(4))) float float4v;

__device__ inline unsigned short f2bf(float f) {   // RNE bf16
    unsigned u = __float_as_uint(f);
    return (unsigned short)((u + 0x7FFF + ((u >> 16) & 1)) >> 16);
}
__device__ inline float bf2f(unsigned short b) {
    return __uint_as_float((unsigned)b << 16);
}

// Per code-tile ct (16 codes): bias (exact fp32, sequential d), et (fp32
// transposed codebook for gather/fallback), and Bh/Bl bf16 packs laid out in
// the exact 16x16x32 B-fragment order: element (lane l, j) = E[kc*32 +
// (l>>4)*8 + j][ct*16 + (l&15)].
__global__ __launch_bounds__(256) void vq_prep(const float* __restrict__ emb,
                                               float* __restrict__ et,
                                               float* __restrict__ bias,
                                               short* __restrict__ Bh,
                                               short* __restrict__ Bl) {
    __shared__ float tile[DD][17];
    const int ct = blockIdx.x;            // 0..31
    const int t  = threadIdx.x;

    {   // stage emb[d][ct*16..+16] -> tile[d][c]
        const int d = t >> 2, c0 = (t & 3) * 4;
        float4 v = *(const float4*)(emb + (size_t)d * KC + ct * 16 + c0);
        tile[d][c0 + 0] = v.x; tile[d][c0 + 1] = v.y;
        tile[d][c0 + 2] = v.z; tile[d][c0 + 3] = v.w;
    }
    __syncthreads();

    if (t < 16) {   // bias, exact sequential d-order
        float s = 0.f;
        #pragma unroll
        for (int d = 0; d < DD; ++d) { float v = tile[d][t]; s += v * v; }
        bias[ct * 16 + t] = s;
    }

    {   // et[(ct*16+c)][d0..d0+3]
        const int c = t >> 4, d0 = (t & 15) * 4;
        float4 v;
        v.x = tile[d0 + 0][c]; v.y = tile[d0 + 1][c];
        v.z = tile[d0 + 2][c]; v.w = tile[d0 + 3][c];
        *(float4*)(et + (size_t)(ct * 16 + c) * DD + d0) = v;
    }

    {   // B-fragment packs
        const int term = t >> 7;          // 0 = hi, 1 = lo
        const int kc   = (t >> 6) & 1;
        const int l    = t & 63;
        const int c    = l & 15, dq = l >> 4;
        short v8[8];
        #pragma unroll
        for (int j = 0; j < 8; ++j) {
            float f = tile[kc * 32 + dq * 8 + j][c];
            unsigned short h = f2bf(f);
            v8[j] = (short)(term == 0 ? h : f2bf(f - bf2f(h)));
        }
        short* dst = (term == 0 ? Bh : Bl) + ((size_t)(ct * 2 + kc) * 64 + l) * 8;
        *(short8*)dst = *(short8*)v8;
    }
}

// Block = 1024 threads / 16 waves, covers 512 rows; wave w owns rows
// [w*32, w*32+32) in registers and sweeps all 512 codes from LDS.
__global__ __launch_bounds__(1024, 4) void vq_main(const float* __restrict__ x_in,
                                                   const short* __restrict__ Bh,
                                                   const short* __restrict__ Bl,
                                                   const float* __restrict__ bias,
                                                   const float* __restrict__ et,
                                                   float* __restrict__ out) {
    __shared__ __align__(16) short Bh_lds[32 * 2 * 64 * 8];   // 64 KB
    __shared__ __align__(16) short Bl_lds[32 * 2 * 64 * 8];   // 64 KB
    __shared__ float bias_s[KC];                               // 2 KB
    __shared__ int   k1s[16][32];
    __shared__ float gaps[16][32];

    const int t = threadIdx.x, w = t >> 6, l = t & 63;
    const int col = l & 15, quad = l >> 4;
    const int R0 = blockIdx.x * 512;
    const int wrow0 = w * 32;

    {   // stage Bh/Bl/bias -> LDS (coalesced float4 copies)
        const float4* srcH = (const float4*)Bh;
        const float4* srcL = (const float4*)Bl;
        float4* dstH = (float4*)Bh_lds;
        float4* dstL = (float4*)Bl_lds;
        #pragma unroll
        for (int j = 0; j < 4; ++j) {
            const int idx = t + j * 1024;             // 4096 float4 per array
            dstH[idx] = srcH[idx];
            dstL[idx] = srcL[idx];
        }
        if (t < KC) bias_s[t] = bias[t];
    }

    // ---- A: this wave's 32 rows -> registers, bf16 hi/lo split (done once).
    // 16x16x32 A-layout: m = lane&15, k = quad*8 + j; rt = 16-row tile 0..1.
    short8 AH[2][2], AL[2][2];
    #pragma unroll
    for (int rt = 0; rt < 2; ++rt)
        #pragma unroll
        for (int kc = 0; kc < 2; ++kc) {
            const float* p = x_in + (size_t)(R0 + wrow0 + rt * 16 + col) * DD
                           + kc * 32 + quad * 8;
            float4 xa = *(const float4*)p;
            float4 xb = *(const float4*)(p + 4);
            float f[8] = {xa.x, xa.y, xa.z, xa.w, xb.x, xb.y, xb.z, xb.w};
            short8 hi8, lo8;
            #pragma unroll
            for (int j = 0; j < 8; ++j) {
                unsigned short h = f2bf(f[j]);
                hi8[j] = (short)h;
                lo8[j] = (short)f2bf(f[j] - bf2f(h));
            }
            AH[rt][kc] = hi8;
            AL[rt][kc] = lo8;
        }
    __syncthreads();   // B staged (the only block-wide barrier before reduce)

    // per-(row,code-lane) running max1/max2/k in c-space (c = x.e - b/2)
    float m1[2][4], m2[2][4];
    int   kb[2][4];
    #pragma unroll
    for (int rt = 0; rt < 2; ++rt)
        #pragma unroll
        for (int r = 0; r < 4; ++r) {
            m1[rt][r] = -3.4e38f; m2[rt][r] = -3.4e38f; kb[rt][r] = 0;
        }

    #pragma unroll 2
    for (int ct = 0; ct < 32; ++ct) {
        short8 bh0 = *(const short8*)&Bh_lds[((ct * 2 + 0) * 64 + l) * 8];
        short8 bh1 = *(const short8*)&Bh_lds[((ct * 2 + 1) * 64 + l) * 8];
        short8 bl0 = *(const short8*)&Bl_lds[((ct * 2 + 0) * 64 + l) * 8];
        short8 bl1 = *(const short8*)&Bl_lds[((ct * 2 + 1) * 64 + l) * 8];
        const float ci = -0.5f * bias_s[ct * 16 + col];
        const int kk = ct * 16 + col;
        #pragma unroll
        for (int rt = 0; rt < 2; ++rt) {
            float4v c = {ci, ci, ci, ci};
            c = __builtin_amdgcn_mfma_f32_16x16x32_bf16(AH[rt][0], bh0, c, 0, 0, 0);
            c = __builtin_amdgcn_mfma_f32_16x16x32_bf16(AH[rt][1], bh1, c, 0, 0, 0);
            c = __builtin_amdgcn_mfma_f32_16x16x32_bf16(AL[rt][0], bh0, c, 0, 0, 0);
            c = __builtin_amdgcn_mfma_f32_16x16x32_bf16(AL[rt][1], bh1, c, 0, 0, 0);
            c = __builtin_amdgcn_mfma_f32_16x16x32_bf16(AH[rt][0], bl0, c, 0, 0, 0);
            c = __builtin_amdgcn_mfma_f32_16x16x32_bf16(AH[rt][1], bl1, c, 0, 0, 0);
            #pragma unroll
            for (int r = 0; r < 4; ++r) {
                float cr = c[r];
                bool gt = cr > m1[rt][r];                    // strict: first-min k
                m2[rt][r] = fmaxf(fminf(cr, m1[rt][r]), m2[rt][r]);
                kb[rt][r] = gt ? kk : kb[rt][r];
                m1[rt][r] = fmaxf(m1[rt][r], cr);
            }
        }
    }

    // reduce over the 16 code-lanes (once per wave); C layout: row =
    // rt*16 + quad*4 + r, col = lane&15.
    #pragma unroll
    for (int rt = 0; rt < 2; ++rt)
        #pragma unroll
        for (int r = 0; r < 4; ++r) {
            float b1 = m1[rt][r], b2 = m2[rt][r];
            int   bk = kb[rt][r];
            #pragma unroll
            for (int m = 1; m <= 8; m <<= 1) {
                float o1 = __shfl_xor(b1, m, 64);
                float o2 = __shfl_xor(b2, m, 64);
                int   ok = __shfl_xor(bk, m, 64);
                float n2 = fmaxf(fmaxf(b2, o2), fminf(b1, o1));
                bool take = (o1 > b1) || (o1 == b1 && ok < bk);
                b1 = take ? o1 : b1;
                bk = take ? ok : bk;
                b2 = n2;
            }
            if (col == 0) {
                const int rowl = rt * 16 + quad * 4 + r;
                k1s[w][rowl]  = bk;
                gaps[w][rowl] = b1 - b2;     // c-space gap = s-gap / 2
            }
        }
    __syncthreads();   // make k1s/gaps visible (cheap, once)

    {   // exact fp32 fallback for near-tie rows (ballot-driven, rare).
        // Lane l scans codes [8l,8l+8) ascending; cross-lane tie-break =
        // lower k => numpy first-min semantics, independent of approx path.
        unsigned long long mask = __ballot((l < 32) && (gaps[w][l] <= HTAU));
        while (mask) {
            const int rr = __builtin_ctzll(mask);
            mask &= mask - 1;
            const size_t grow = (size_t)(R0 + wrow0 + rr) * DD;
            const int kbase = l * 8;
            float acc[8];
            #pragma unroll
            for (int j = 0; j < 8; ++j) acc[j] = 0.f;
            for (int d0 = 0; d0 < DD; d0 += 4) {
                float4 xv = *(const float4*)(x_in + grow + d0);
                #pragma unroll
                for (int j = 0; j < 8; ++j) {
                    float4 ev = *(const float4*)(et + (size_t)(kbase + j) * DD + d0);
                    acc[j] += xv.x * ev.x;
                    acc[j] += xv.y * ev.y;
                    acc[j] += xv.z * ev.z;
                    acc[j] += xv.w * ev.w;
                }
            }
            float4 b0 = *(const float4*)(bias + kbase);
            float4 b1v = *(const float4*)(bias + kbase + 4);
            float bb[8] = {b0.x, b0.y, b0.z, b0.w, b1v.x, b1v.y, b1v.z, b1v.w};
            float bv = 3.4e38f; int bk = 0;
            #pragma unroll
            for (int j = 0; j < 8; ++j) {
                float s = bb[j] - 2.f * acc[j];
                if (s < bv) { bv = s; bk = kbase + j; }
            }
            #pragma unroll
            for (int m = 1; m <= 32; m <<= 1) {
                float ov = __shfl_xor(bv, m, 64);
                int   ok = __shfl_xor(bk, m, 64);
                if (ov < bv || (ov == bv && ok < bk)) { bv = ov; bk = ok; }
            }
            if (l == 0) k1s[w][rr] = bk;
        }
    }

    {   // gather epilogue (per wave, its own rows): 16 lanes per row
        const int c4 = col * 4;
        #pragma unroll
        for (int i = 0; i < 8; ++i) {
            const int rowl = i * 4 + quad;
            const int bk = k1s[w][rowl];
            float4 v = *(const float4*)(et + (size_t)bk * DD + c4);
            *(float4*)(out + (size_t)(R0 + wrow0 + rowl) * DD + c4) = v;
        }
    }
}

extern "C" void kernel_launch(void* const* d_in, const int* in_sizes, int n_in,
                              void* d_out, int out_size, void* d_ws, size_t ws_size,
                              hipStream_t stream) {
    const float* x_in = (const float*)d_in[0];   // [131072, 64]
    const float* emb  = (const float*)d_in[1];   // [64, 512]
    float* out = (float*)d_out;

    float* et   = (float*)d_ws;                       // 512*64 f32 = 131072 B
    float* bias = et + KC * DD;                       // 2048 B
    short* Bh   = (short*)(bias + KC);                // 32*2*64*8 shorts = 64 KB
    short* Bl   = Bh + 32 * 2 * 64 * 8;               // 64 KB

    const int N = out_size / DD;                      // 131072 rows

    vq_prep<<<32, 256, 0, stream>>>(emb, et, bias, Bh, Bl);
    vq_main<<<N / 512, 1024, 0, stream>>>(x_in, Bh, Bl, bias, et, out);
}